// Round 1
// baseline (27.227 us; speedup 1.0000x reference)
//
#include <hip/hip_runtime.h>
#include <hip/hip_bf16.h>

#define N_QUBITS 4
#define BATCH_TOTAL 524288

// ---------------------------------------------------------------------------
// Prep kernel: compute the 8 Rot(phi,theta,omega) matrices (2 layers x 4
// wires) from `weights` into ws as [l][q][8] floats:
//   {m00.re, m00.im, m01.re, m01.im, m10.re, m10.im, m11.re, m11.im}
// Rot = RZ(omega) RY(theta) RZ(phi):
//   m00 =  e^{-i(phi+om)/2} cos(th/2)
//   m01 = -e^{ i(phi-om)/2} sin(th/2)
//   m10 =  e^{-i(phi-om)/2} sin(th/2)
//   m11 =  e^{ i(phi+om)/2} cos(th/2)
// ---------------------------------------------------------------------------
__global__ void qprep_kernel(const float* __restrict__ w, float* __restrict__ mats) {
    int t = threadIdx.x;
    if (t >= 8) return;
    float phi = w[t * 3 + 0];
    float th  = w[t * 3 + 1];
    float om  = w[t * 3 + 2];
    float ct = cosf(0.5f * th);
    float st = sinf(0.5f * th);
    float sp, cp, sm, cm;
    sincosf(0.5f * (phi + om), &sp, &cp);
    sincosf(0.5f * (phi - om), &sm, &cm);
    float* m = mats + t * 8;
    m[0] =  cp * ct;  m[1] = -sp * ct;   // m00
    m[2] = -cm * st;  m[3] = -sm * st;   // m01
    m[4] =  cm * st;  m[5] = -sm * st;   // m10
    m[6] =  cp * ct;  m[7] =  sp * ct;   // m11
}

// ---------------------------------------------------------------------------
// Main kernel: one thread per batch element. 16 complex amplitudes in
// registers. Wire q <-> bit (3-q) of the flat index (wire 0 most significant).
// ---------------------------------------------------------------------------
__global__ __launch_bounds__(256) void qsim_kernel(
    const float4* __restrict__ x,      // [B] of float4 (4 angles)
    const float*  __restrict__ mats,   // [2][4][8] rot matrices (uniform)
    const float*  __restrict__ fcw,    // [2][2]
    const float*  __restrict__ fcb,    // [2]
    float2*       __restrict__ out,    // [B] of float2
    int B)
{
    int b = blockIdx.x * blockDim.x + threadIdx.x;
    if (b >= B) return;

    float4 xv = x[b];
    float c[4], s[4];
    __sincosf(0.5f * xv.x, &s[0], &c[0]);
    __sincosf(0.5f * xv.y, &s[1], &c[1]);
    __sincosf(0.5f * xv.z, &s[2], &c[2]);
    __sincosf(0.5f * xv.w, &s[3], &c[3]);

    // Initial product state after RX embedding on |0000>:
    // amp(idx) = prod_q (bit_q ? sin : cos) * (-i)^popcount(idx)
    float re[16], im[16];
#pragma unroll
    for (int idx = 0; idx < 16; ++idx) {
        float p = ((idx & 8) ? s[0] : c[0]);
        p      *= ((idx & 4) ? s[1] : c[1]);
        p      *= ((idx & 2) ? s[2] : c[2]);
        p      *= ((idx & 1) ? s[3] : c[3]);
        int k = __popc(idx) & 3;   // (-i)^k
        re[idx] = (k == 0) ? p : ((k == 2) ? -p : 0.0f);
        im[idx] = (k == 1) ? -p : ((k == 3) ? p : 0.0f);
    }

    // StronglyEntanglingLayers: 2 layers of (4 Rot gates + ring of CNOTs)
#pragma unroll
    for (int l = 0; l < 2; ++l) {
#pragma unroll
        for (int q = 0; q < N_QUBITS; ++q) {
            const float* m = mats + (l * 4 + q) * 8;
            float m00r = m[0], m00i = m[1];
            float m01r = m[2], m01i = m[3];
            float m10r = m[4], m10i = m[5];
            float m11r = m[6], m11i = m[7];
            const int bit = 8 >> q;
#pragma unroll
            for (int i = 0; i < 16; ++i) {
                if (i & bit) continue;
                const int j = i | bit;
                float a0r = re[i], a0i = im[i];
                float a1r = re[j], a1i = im[j];
                re[i] = m00r * a0r - m00i * a0i + m01r * a1r - m01i * a1i;
                im[i] = m00r * a0i + m00i * a0r + m01r * a1i + m01i * a1r;
                re[j] = m10r * a0r - m10i * a0i + m11r * a1r - m11i * a1i;
                im[j] = m10r * a0i + m10i * a0r + m11r * a1i + m11i * a1r;
            }
        }
        // CNOT ring: control q, target (q+r)%4, r = l%3+1
        const int r = (l % 3) + 1;
#pragma unroll
        for (int q = 0; q < N_QUBITS; ++q) {
            const int cbit = 8 >> q;
            const int tbit = 8 >> ((q + r) & 3);
#pragma unroll
            for (int i = 0; i < 16; ++i) {
                if ((i & cbit) && !(i & tbit)) {
                    const int j = i | tbit;
                    float tr = re[i]; re[i] = re[j]; re[j] = tr;
                    float ti = im[i]; im[i] = im[j]; im[j] = ti;
                }
            }
        }
    }

    // <Z0>, <Z1>
    float z0 = 0.0f, z1 = 0.0f;
#pragma unroll
    for (int i = 0; i < 16; ++i) {
        float p = re[i] * re[i] + im[i] * im[i];
        z0 += (i & 8) ? -p : p;
        z1 += (i & 4) ? -p : p;
    }

    // Linear(2,2): out[b][j] = z0*fcw[j][0] + z1*fcw[j][1] + fcb[j]
    float w00 = fcw[0], w01 = fcw[1], w10 = fcw[2], w11 = fcw[3];
    float b0 = fcb[0], b1 = fcb[1];
    float2 o;
    o.x = fmaf(z0, w00, fmaf(z1, w01, b0));
    o.y = fmaf(z0, w10, fmaf(z1, w11, b1));
    out[b] = o;
}

extern "C" void kernel_launch(void* const* d_in, const int* in_sizes, int n_in,
                              void* d_out, int out_size, void* d_ws, size_t ws_size,
                              hipStream_t stream) {
    const float* x   = (const float*)d_in[0];   // [B,4] f32
    const float* w   = (const float*)d_in[1];   // [2,4,3] f32
    const float* fcw = (const float*)d_in[2];   // [2,2] f32
    const float* fcb = (const float*)d_in[3];   // [2] f32
    float* out = (float*)d_out;                 // [B,2] f32
    float* mats = (float*)d_ws;                 // 64 floats

    int B = in_sizes[0] / 4;

    qprep_kernel<<<1, 64, 0, stream>>>(w, mats);

    int threads = 256;
    int blocks = (B + threads - 1) / threads;
    qsim_kernel<<<blocks, threads, 0, stream>>>(
        (const float4*)x, mats, fcw, fcb, (float2*)out, B);
}

// Round 2
// 18.942 us; speedup vs baseline: 1.4374x; 1.4374x over previous
//
#include <hip/hip_runtime.h>
#include <hip/hip_bf16.h>

// ---------------------------------------------------------------------------
// HybridQuantumNet: 4-qubit default.qubit sim + Linear(2,2), B = 524288.
//
// Algebraic reduction: circuit after RX-embedding is a fixed 16x16 unitary U
// (weights-only). Outputs: z_q = psi0^dag (U^dag Z_q U) psi0 with psi0 a
// product state; per-qubit density factor is affine in (1, cos x_q, sin x_q).
// => out[b][o] = sum_{k in 3^4} C[k][o] * prod_q g_{k_q}(x_q),
//    g = (1, cos, sin); fc_w/fc_b folded into C (162 floats, in d_ws).
// ---------------------------------------------------------------------------

// ===========================================================================
// Prep kernel (1 block x 256 threads): weights -> coefficient table C[81][2].
// ===========================================================================
__global__ void qprep_kernel(const float* __restrict__ w,    // [2][4][3]
                             const float* __restrict__ fcw,  // [2][2]
                             const float* __restrict__ fcb,  // [2]
                             float* __restrict__ C)          // [81][2]
{
    __shared__ float rot[8][8];       // 8 Rot gates, {m00r,m00i,m01r,m01i,m10r,m10i,m11r,m11i}
    __shared__ float Ur[16][16];      // U[k][col]
    __shared__ float Ui[16][16];
    __shared__ float Mr[2][16][16];   // M_o = U^dag Z_o U
    __shared__ float Mi[2][16][16];

    const int t = threadIdx.x;

    // --- 1: Rot matrices. Rot = RZ(om) RY(th) RZ(phi). ---
    if (t < 8) {
        float phi = w[t*3+0], th = w[t*3+1], om = w[t*3+2];
        float ct = cosf(0.5f*th), st = sinf(0.5f*th);
        float sp, cp, sm, cm;
        sincosf(0.5f*(phi+om), &sp, &cp);
        sincosf(0.5f*(phi-om), &sm, &cm);
        rot[t][0] =  cp*ct;  rot[t][1] = -sp*ct;   // m00
        rot[t][2] = -cm*st;  rot[t][3] = -sm*st;   // m01
        rot[t][4] =  cm*st;  rot[t][5] = -sm*st;   // m10
        rot[t][6] =  cp*ct;  rot[t][7] =  sp*ct;   // m11
    }
    __syncthreads();

    // --- 2: build U columns (wire q <-> bit (3-q), wire 0 most significant) ---
    if (t < 16) {
        float re[16], im[16];
#pragma unroll
        for (int i = 0; i < 16; ++i) { re[i] = 0.0f; im[i] = 0.0f; }
        re[t] = 1.0f;
#pragma unroll
        for (int l = 0; l < 2; ++l) {
#pragma unroll
            for (int q = 0; q < 4; ++q) {
                const float* m = rot[l*4 + q];
                float m00r=m[0],m00i=m[1],m01r=m[2],m01i=m[3];
                float m10r=m[4],m10i=m[5],m11r=m[6],m11i=m[7];
                const int bit = 8 >> q;
#pragma unroll
                for (int i = 0; i < 16; ++i) {
                    if (i & bit) continue;
                    const int j = i | bit;
                    float a0r=re[i], a0i=im[i], a1r=re[j], a1i=im[j];
                    re[i] = m00r*a0r - m00i*a0i + m01r*a1r - m01i*a1i;
                    im[i] = m00r*a0i + m00i*a0r + m01r*a1i + m01i*a1r;
                    re[j] = m10r*a0r - m10i*a0i + m11r*a1r - m11i*a1i;
                    im[j] = m10r*a0i + m10i*a0r + m11r*a1i + m11i*a1r;
                }
            }
            const int r = (l % 3) + 1;
#pragma unroll
            for (int q = 0; q < 4; ++q) {
                const int cbit = 8 >> q;
                const int tbit = 8 >> ((q + r) & 3);
#pragma unroll
                for (int i = 0; i < 16; ++i) {
                    if ((i & cbit) && !(i & tbit)) {
                        const int j = i | tbit;
                        float tr = re[i]; re[i] = re[j]; re[j] = tr;
                        float ti = im[i]; im[i] = im[j]; im[j] = ti;
                    }
                }
            }
        }
#pragma unroll
        for (int k = 0; k < 16; ++k) { Ur[k][t] = re[k]; Ui[k][t] = im[k]; }
    }
    __syncthreads();

    // --- 3: M_o[i][j] = sum_k (+-1) conj(U[k][i]) U[k][j], o=0: sign bit8, o=1: bit4 ---
    {
        const int i = t >> 4, j = t & 15;
        float r0=0, i0=0, r1=0, i1=0;
#pragma unroll
        for (int k = 0; k < 16; ++k) {
            float ar = Ur[k][i], ai = Ui[k][i];   // conjugated
            float br = Ur[k][j], bi = Ui[k][j];
            float pr = ar*br + ai*bi;
            float pi = ar*bi - ai*br;
            float sg0 = (k & 8) ? -1.0f : 1.0f;
            float sg1 = (k & 4) ? -1.0f : 1.0f;
            r0 += sg0*pr; i0 += sg0*pi;
            r1 += sg1*pr; i1 += sg1*pi;
        }
        Mr[0][i][j] = r0; Mi[0][i][j] = i0;
        Mr[1][i][j] = r1; Mi[1][i][j] = i1;
    }
    __syncthreads();

    // --- 4: project onto {I', Z', S'} basis per qubit; fold fc. ---
    // v_q = (1/2)[(1+c), -i s; i s, (1-c)] = B0*1 + B1*c + B2*s with
    // B0=diag(1,1)/2, B1=diag(1,-1)/2, B2=[[0,-i],[i,0]]/2.
    // C[k] = sum_{i} M[i][i^mask2] * (1/16) * (-1)^popc(mask1&i) * i^(a-b),
    //   mask2 = bits with k_q==2, mask1 = bits with k_q==1,
    //   a = popc(mask2&i), b = popc(mask2)-a.
    if (t < 81) {
        const int k3 = t % 3, k2 = (t/3) % 3, k1 = (t/9) % 3, k0 = t / 27;
        const int kd[4] = {k0, k1, k2, k3};
        int mask2 = 0, mask1 = 0;
#pragma unroll
        for (int q = 0; q < 4; ++q) {
            const int bit = 8 >> q;
            if (kd[q] == 2) mask2 |= bit;
            else if (kd[q] == 1) mask1 |= bit;
        }
        float z[2];
#pragma unroll
        for (int o = 0; o < 2; ++o) {
            float cr = 0.0f;
            for (int i = 0; i < 16; ++i) {
                const int j = i ^ mask2;
                const float mr = Mr[o][i][j], mi = Mi[o][i][j];
                const int s1 = __popc(mask1 & i) & 1;
                const int a  = __popc(mask2 & i);
                const int bb = __popc(mask2) - a;
                const int ip = ((a - bb) % 4 + 4) & 3;
                float wr, wi;
                switch (ip) {
                    case 0:  wr =  1.0f; wi =  0.0f; break;
                    case 1:  wr =  0.0f; wi =  1.0f; break;
                    case 2:  wr = -1.0f; wi =  0.0f; break;
                    default: wr =  0.0f; wi = -1.0f; break;
                }
                if (s1) { wr = -wr; wi = -wi; }
                cr += wr*mr - wi*mi;     // real part of w * M
            }
            z[o] = cr * 0.0625f;
        }
#pragma unroll
        for (int o = 0; o < 2; ++o) {
            float v = z[0]*fcw[o*2+0] + z[1]*fcw[o*2+1];
            if (t == 0) v += fcb[o];
            C[t*2 + o] = v;
        }
    }
}

// ===========================================================================
// Main kernel: 4 sincos + 160 FMA per thread (4-stage contraction).
// ===========================================================================
__global__ __launch_bounds__(256) void qmain_kernel(
    const float4* __restrict__ x,    // [B] angles
    const float*  __restrict__ C,    // [81][2] coefficients (uniform)
    float2*       __restrict__ out,  // [B]
    int B)
{
    const int b = blockIdx.x * blockDim.x + threadIdx.x;
    if (b >= B) return;

    const float4 xv = x[b];
    float c0,s0,c1,s1,c2,s2,c3,s3;
    __sincosf(xv.x, &s0, &c0);
    __sincosf(xv.y, &s1, &c1);
    __sincosf(xv.z, &s2, &c2);
    __sincosf(xv.w, &s3, &c3);

    float a2[54];
#pragma unroll
    for (int m = 0; m < 54; ++m)
        a2[m] = fmaf(s0, C[108+m], fmaf(c0, C[54+m], C[m]));

    float a3[18];
#pragma unroll
    for (int m = 0; m < 18; ++m)
        a3[m] = fmaf(s1, a2[36+m], fmaf(c1, a2[18+m], a2[m]));

    float a4[6];
#pragma unroll
    for (int m = 0; m < 6; ++m)
        a4[m] = fmaf(s2, a3[12+m], fmaf(c2, a3[6+m], a3[m]));

    float2 o;
    o.x = fmaf(s3, a4[4], fmaf(c3, a4[2], a4[0]));
    o.y = fmaf(s3, a4[5], fmaf(c3, a4[3], a4[1]));
    out[b] = o;
}

extern "C" void kernel_launch(void* const* d_in, const int* in_sizes, int n_in,
                              void* d_out, int out_size, void* d_ws, size_t ws_size,
                              hipStream_t stream) {
    const float* x   = (const float*)d_in[0];   // [B,4]
    const float* w   = (const float*)d_in[1];   // [2,4,3]
    const float* fcw = (const float*)d_in[2];   // [2,2]
    const float* fcb = (const float*)d_in[3];   // [2]
    float* out = (float*)d_out;                 // [B,2]
    float* C   = (float*)d_ws;                  // 162 floats

    const int B = in_sizes[0] / 4;

    qprep_kernel<<<1, 256, 0, stream>>>(w, fcw, fcb, C);

    const int threads = 256;
    const int blocks = (B + threads - 1) / threads;
    qmain_kernel<<<blocks, threads, 0, stream>>>(
        (const float4*)x, C, (float2*)out, B);
}

// Round 3
// 18.138 us; speedup vs baseline: 1.5011x; 1.0444x over previous
//
#include <hip/hip_runtime.h>
#include <hip/hip_bf16.h>

// ---------------------------------------------------------------------------
// HybridQuantumNet: 4-qubit default.qubit sim + Linear(2,2), B = 524288.
//
// out[b][o] = sum_{k in 3^4} C[k][o] * prod_q g_{k_q}(x_q), g = (1, cos, sin).
// C (162 floats, weights/fc-only) is computed per-block (redundantly) into a
// private d_ws slice, then contracted per element: 4 sincos + ~160 FMA.
// Single fused kernel: 512 blocks x 256 threads x 4 elements/thread.
// ---------------------------------------------------------------------------

#define NBLK 512
#define NTHR 256
#define EPT  4                       // elements per thread
#define CSLICE 256                   // floats per block slice in ws (1 KB)

__global__ __launch_bounds__(256) void qfused_kernel(
    const float4* __restrict__ x,    // [B] angle quads
    const float*  __restrict__ w,    // [2][4][3]
    const float*  __restrict__ fcw,  // [2][2]
    const float*  __restrict__ fcb,  // [2]
    float*        __restrict__ ws,   // >= NBLK*CSLICE floats
    float2*       __restrict__ out,  // [B]
    int B)
{
    __shared__ float rot[8][8];
    __shared__ float Ur[16][16], Ui[16][16];
    __shared__ float Mr[2][16][16], Mi[2][16][16];

    const int t = threadIdx.x;
    const int stride = NBLK * NTHR;
    const int base = blockIdx.x * NTHR + t;
    float* Cg = ws + (size_t)blockIdx.x * CSLICE;

    // Issue the streaming x-loads up front; latency hides under prep.
    float4 xv[EPT];
#pragma unroll
    for (int e = 0; e < EPT; ++e) {
        int el = base + e * stride;
        if (el < B) xv[e] = x[el];
    }

    // ===================== per-block prep: weights -> C ====================
    // 1: Rot matrices. Rot = RZ(om) RY(th) RZ(phi).
    if (t < 8) {
        float phi = w[t*3+0], th = w[t*3+1], om = w[t*3+2];
        float ct = cosf(0.5f*th), st = sinf(0.5f*th);
        float sp, cp, sm, cm;
        sincosf(0.5f*(phi+om), &sp, &cp);
        sincosf(0.5f*(phi-om), &sm, &cm);
        rot[t][0] =  cp*ct;  rot[t][1] = -sp*ct;
        rot[t][2] = -cm*st;  rot[t][3] = -sm*st;
        rot[t][4] =  cm*st;  rot[t][5] = -sm*st;
        rot[t][6] =  cp*ct;  rot[t][7] =  sp*ct;
    }
    __syncthreads();

    // 2: build U columns (wire q <-> bit (3-q))
    if (t < 16) {
        float re[16], im[16];
#pragma unroll
        for (int i = 0; i < 16; ++i) { re[i] = 0.0f; im[i] = 0.0f; }
        re[t] = 1.0f;
#pragma unroll
        for (int l = 0; l < 2; ++l) {
#pragma unroll
            for (int q = 0; q < 4; ++q) {
                const float* m = rot[l*4 + q];
                float m00r=m[0],m00i=m[1],m01r=m[2],m01i=m[3];
                float m10r=m[4],m10i=m[5],m11r=m[6],m11i=m[7];
                const int bit = 8 >> q;
#pragma unroll
                for (int i = 0; i < 16; ++i) {
                    if (i & bit) continue;
                    const int j = i | bit;
                    float a0r=re[i], a0i=im[i], a1r=re[j], a1i=im[j];
                    re[i] = m00r*a0r - m00i*a0i + m01r*a1r - m01i*a1i;
                    im[i] = m00r*a0i + m00i*a0r + m01r*a1i + m01i*a1r;
                    re[j] = m10r*a0r - m10i*a0i + m11r*a1r - m11i*a1i;
                    im[j] = m10r*a0i + m10i*a0r + m11r*a1i + m11i*a1r;
                }
            }
            const int r = (l % 3) + 1;
#pragma unroll
            for (int q = 0; q < 4; ++q) {
                const int cbit = 8 >> q;
                const int tbit = 8 >> ((q + r) & 3);
#pragma unroll
                for (int i = 0; i < 16; ++i) {
                    if ((i & cbit) && !(i & tbit)) {
                        const int j = i | tbit;
                        float tr = re[i]; re[i] = re[j]; re[j] = tr;
                        float ti = im[i]; im[i] = im[j]; im[j] = ti;
                    }
                }
            }
        }
#pragma unroll
        for (int k = 0; k < 16; ++k) { Ur[k][t] = re[k]; Ui[k][t] = im[k]; }
    }
    __syncthreads();

    // 3: M_o = U^dag Z_o U  (o=0: sign bit8, o=1: sign bit4)
    {
        const int i = t >> 4, j = t & 15;
        float r0=0, i0=0, r1=0, i1=0;
#pragma unroll
        for (int k = 0; k < 16; ++k) {
            float ar = Ur[k][i], ai = Ui[k][i];
            float br = Ur[k][j], bi = Ui[k][j];
            float pr = ar*br + ai*bi;
            float pi = ar*bi - ai*br;
            float sg0 = (k & 8) ? -1.0f : 1.0f;
            float sg1 = (k & 4) ? -1.0f : 1.0f;
            r0 += sg0*pr; i0 += sg0*pi;
            r1 += sg1*pr; i1 += sg1*pi;
        }
        Mr[0][i][j] = r0; Mi[0][i][j] = i0;
        Mr[1][i][j] = r1; Mi[1][i][j] = i1;
    }
    __syncthreads();

    // 4: project onto per-qubit {1, cos, sin} basis, fold fc, write Cg.
    // Layout: Cg[k0*64 + (k1*9+k2*3+k3)*2 + o]  (3 segments of 54, 256B apart)
    if (t < 81) {
        const int k3 = t % 3, k2 = (t/3) % 3, k1 = (t/9) % 3, k0 = t / 27;
        const int kd[4] = {k0, k1, k2, k3};
        int mask2 = 0, mask1 = 0;
#pragma unroll
        for (int q = 0; q < 4; ++q) {
            const int bit = 8 >> q;
            if (kd[q] == 2) mask2 |= bit;
            else if (kd[q] == 1) mask1 |= bit;
        }
        float z[2];
#pragma unroll
        for (int o = 0; o < 2; ++o) {
            float cr = 0.0f;
            for (int i = 0; i < 16; ++i) {
                const int j = i ^ mask2;
                const float mr = Mr[o][i][j], mi = Mi[o][i][j];
                const int s1 = __popc(mask1 & i) & 1;
                const int a  = __popc(mask2 & i);
                const int bb = __popc(mask2) - a;
                const int ip = ((a - bb) % 4 + 4) & 3;
                float wr, wi;
                switch (ip) {
                    case 0:  wr =  1.0f; wi =  0.0f; break;
                    case 1:  wr =  0.0f; wi =  1.0f; break;
                    case 2:  wr = -1.0f; wi =  0.0f; break;
                    default: wr =  0.0f; wi = -1.0f; break;
                }
                if (s1) { wr = -wr; wi = -wi; }
                cr += wr*mr - wi*mi;
            }
            z[o] = cr * 0.0625f;
        }
        const int rest = (t % 27) * 2;
#pragma unroll
        for (int o = 0; o < 2; ++o) {
            float v = z[0]*fcw[o*2+0] + z[1]*fcw[o*2+1];
            if (t == 0) v += fcb[o];
            Cg[k0*64 + rest + o] = v;
        }
    }
    __syncthreads();

    // ===================== main: 2 pairs of elements ======================
#pragma unroll
    for (int pp = 0; pp < EPT / 2; ++pp) {
        const int eA = 2*pp, eB = 2*pp + 1;
        float cA[4], sA[4], cB[4], sB[4];
        __sincosf(xv[eA].x, &sA[0], &cA[0]);
        __sincosf(xv[eA].y, &sA[1], &cA[1]);
        __sincosf(xv[eA].z, &sA[2], &cA[2]);
        __sincosf(xv[eA].w, &sA[3], &cA[3]);
        __sincosf(xv[eB].x, &sB[0], &cB[0]);
        __sincosf(xv[eB].y, &sB[1], &cB[1]);
        __sincosf(xv[eB].z, &sB[2], &cB[2]);
        __sincosf(xv[eB].w, &sB[3], &cB[3]);

        float a2A[54], a2B[54];
#define S1(mm, v0, v1, v2)                                      \
        if ((mm) < 54) {                                        \
            a2A[mm] = fmaf(sA[0], v2, fmaf(cA[0], v1, v0));     \
            a2B[mm] = fmaf(sB[0], v2, fmaf(cB[0], v1, v0));     \
        }
#pragma unroll
        for (int mq = 0; mq < 14; ++mq) {
            const float4 q0 = *(const float4*)(Cg +       mq*4);
            const float4 q1 = *(const float4*)(Cg +  64 + mq*4);
            const float4 q2 = *(const float4*)(Cg + 128 + mq*4);
            S1(mq*4+0, q0.x, q1.x, q2.x);
            S1(mq*4+1, q0.y, q1.y, q2.y);
            S1(mq*4+2, q0.z, q1.z, q2.z);
            S1(mq*4+3, q0.w, q1.w, q2.w);
        }
#undef S1

#pragma unroll
        for (int half = 0; half < 2; ++half) {
            const float* a2 = half ? a2B : a2A;
            const float* cc = half ? cB : cA;
            const float* ss = half ? sB : sA;
            float a3[18];
#pragma unroll
            for (int n = 0; n < 18; ++n)
                a3[n] = fmaf(ss[1], a2[36+n], fmaf(cc[1], a2[18+n], a2[n]));
            float a4[6];
#pragma unroll
            for (int p = 0; p < 6; ++p)
                a4[p] = fmaf(ss[2], a3[12+p], fmaf(cc[2], a3[6+p], a3[p]));
            float2 o;
            o.x = fmaf(ss[3], a4[4], fmaf(cc[3], a4[2], a4[0]));
            o.y = fmaf(ss[3], a4[5], fmaf(cc[3], a4[3], a4[1]));
            const int el = base + (2*pp + half) * stride;
            if (el < B) out[el] = o;
        }
    }
}

extern "C" void kernel_launch(void* const* d_in, const int* in_sizes, int n_in,
                              void* d_out, int out_size, void* d_ws, size_t ws_size,
                              hipStream_t stream) {
    const float* x   = (const float*)d_in[0];   // [B,4]
    const float* w   = (const float*)d_in[1];   // [2,4,3]
    const float* fcw = (const float*)d_in[2];   // [2,2]
    const float* fcb = (const float*)d_in[3];   // [2]
    float* out = (float*)d_out;                 // [B,2]
    float* ws  = (float*)d_ws;

    const int B = in_sizes[0] / 4;

    qfused_kernel<<<NBLK, NTHR, 0, stream>>>(
        (const float4*)x, w, fcw, fcb, ws, (float2*)out, B);
}